// Round 3
// baseline (152.316 us; speedup 1.0000x reference)
//
#include <hip/hip_runtime.h>
#include <hip/hip_bf16.h>

#define BB 64
#define PP 576
#define DD 1024
#define HH 512

typedef __attribute__((ext_vector_type(4))) float f32x4;
typedef __attribute__((ext_vector_type(8))) short bf16x8;

__device__ __forceinline__ unsigned short f2bf(float f) {
    union { float f; unsigned u; } v; v.f = f;
    unsigned r = v.u + 0x7FFF + ((v.u >> 16) & 1);
    return (unsigned short)(r >> 16);
}

__device__ __forceinline__ float fast_tanh(float x) {
    float e = __expf(2.f * x);
    return 1.f - 2.f / (e + 1.f);
}

__device__ __forceinline__ void gload16(const void* g, void* l) {
    __builtin_amdgcn_global_load_lds((const __attribute__((address_space(1))) unsigned int*)g,
                                     (__attribute__((address_space(3))) unsigned int*)l,
                                     16, 0, 0);
}

// ---- kernel 0: convert W_img fp32 -> bf16 in ws ----
__global__ __launch_bounds__(256) void k_convert(const float* __restrict__ w,
                                                 unsigned short* __restrict__ o) {
    int i = (blockIdx.x * 256 + threadIdx.x) * 4;
    f32x4 v = *(const f32x4*)(w + i);
    ushort4 r;
    r.x = f2bf(v.x); r.y = f2bf(v.y); r.z = f2bf(v.z); r.w = f2bf(v.w);
    *(ushort4*)(o + i) = r;
}

// ---- kernel 1: g[b][h] = tanh(seq[b]·W_seq[h]) * W_w[h]  (fp32 exact path) ----
__global__ __launch_bounds__(128) void k_seq(const float* __restrict__ seq,
                                             const float* __restrict__ W_seq,
                                             const float* __restrict__ W_w,
                                             float* __restrict__ g) {
    int b = blockIdx.x;
    int h = blockIdx.y * 128 + threadIdx.x;
    __shared__ float s_seq[DD];
    #pragma unroll
    for (int i = 0; i < 8; i++) s_seq[threadIdx.x + i * 128] = seq[b * DD + threadIdx.x + i * 128];
    __syncthreads();
    const float* wr = W_seq + (size_t)h * DD;
    float acc = 0.f;
    #pragma unroll 4
    for (int d = 0; d < DD; d += 4) {
        f32x4 w4 = *(const f32x4*)(wr + d);
        acc += w4.x * s_seq[d] + w4.y * s_seq[d + 1] + w4.z * s_seq[d + 2] + w4.w * s_seq[d + 3];
    }
    g[b * HH + h] = fast_tanh(acc) * W_w[h];
}

// ---- kernel 2: partial scores via bf16 MFMA, double-buffered 2-phase pipeline ----
// Block: 256 thr = 4 waves. Tile: BM=64 rows x HC=256 cols, BK=64 per round, 16 rounds.
// Wave w handles cols [w*64, (w+1)*64): 4x4 frags of 16x16x32.
// LDS rows of 64 bf16 (128B), 16B-chunk XOR-swizzled: chunk_sw = chunk ^ (row&7).
// Pipeline: issue loads(t+1) -> compute(t) -> pack+ds_write(t+1) -> barrier.
__global__ __launch_bounds__(256) void k_scores(const float* __restrict__ img,
                                                const unsigned short* __restrict__ Wb,
                                                const float* __restrict__ g,
                                                float* __restrict__ sp) {
    int b = blockIdx.y;
    int rt = blockIdx.x % 9;
    int ch = blockIdx.x / 9;
    int p0 = rt * 64;
    int h0 = ch * 256;
    int tid = threadIdx.x;
    int w = tid >> 6, lane = tid & 63;

    __shared__ unsigned short As[2][64 * 64];    // 2 x 8 KB
    __shared__ unsigned short Bs[2][256 * 64];   // 2 x 32 KB  -> total 80 KB exactly

    // g values needed by this thread, kept in registers (frees LDS for 2 blocks/CU)
    float gr[4];
    #pragma unroll
    for (int n = 0; n < 4; ++n) gr[n] = g[b * HH + h0 + w * 64 + n * 16 + (lane & 15)];

    f32x4 acc[4][4];
    #pragma unroll
    for (int m = 0; m < 4; m++)
        #pragma unroll
        for (int n = 0; n < 4; n++) acc[m][n] = (f32x4)0.f;

    // A staging geometry: thread t -> row t>>2, 16 cols at (t&3)*16
    int ar = tid >> 2;
    int ac = (tid & 3) * 16;
    const float* asrc = img + ((size_t)(b * PP + p0 + ar)) * DD + ac;
    int cp = (tid & 3) * 2;
    int aw0 = ar * 64 + ((cp ^ (ar & 7)) * 8);
    int aw1 = ar * 64 + (((cp + 1) ^ (ar & 7)) * 8);

    // B staging geometry (global_load_lds, pre-swizzled source)
    int brow_l = lane >> 3;
    int bchunk = lane & 7;

    auto stageB = [&](int bi, int kr) {
        int k0 = kr * 64;
        #pragma unroll
        for (int i = 0; i < 8; ++i) {
            int hr = (w * 8 + i) * 8 + brow_l;
            const unsigned short* src = Wb + (size_t)(h0 + hr) * DD + k0 + ((bchunk ^ (hr & 7)) * 8);
            gload16(src, &Bs[bi][(w * 8 + i) * 512]);
        }
    };
    auto packA = [&](int bi, f32x4 v0, f32x4 v1, f32x4 v2, f32x4 v3) {
        bf16x8 pa, pb;
        pa[0] = (short)f2bf(v0.x); pa[1] = (short)f2bf(v0.y);
        pa[2] = (short)f2bf(v0.z); pa[3] = (short)f2bf(v0.w);
        pa[4] = (short)f2bf(v1.x); pa[5] = (short)f2bf(v1.y);
        pa[6] = (short)f2bf(v1.z); pa[7] = (short)f2bf(v1.w);
        pb[0] = (short)f2bf(v2.x); pb[1] = (short)f2bf(v2.y);
        pb[2] = (short)f2bf(v2.z); pb[3] = (short)f2bf(v2.w);
        pb[4] = (short)f2bf(v3.x); pb[5] = (short)f2bf(v3.y);
        pb[6] = (short)f2bf(v3.z); pb[7] = (short)f2bf(v3.w);
        *(bf16x8*)&As[bi][aw0] = pa;
        *(bf16x8*)&As[bi][aw1] = pb;
    };

    // ---- prologue: stage round 0 into buffer 0 ----
    stageB(0, 0);
    {
        f32x4 v0 = *(const f32x4*)(asrc);
        f32x4 v1 = *(const f32x4*)(asrc + 4);
        f32x4 v2 = *(const f32x4*)(asrc + 8);
        f32x4 v3 = *(const f32x4*)(asrc + 12);
        packA(0, v0, v1, v2, v3);
    }
    __syncthreads();

    f32x4 va0, va1, va2, va3;
    for (int kr = 0; kr < 16; ++kr) {
        int cur = kr & 1, nxt = cur ^ 1;
        // phase 1: issue next round's loads (async; fly under compute)
        if (kr < 15) {
            stageB(nxt, kr + 1);
            int k0 = (kr + 1) * 64;
            va0 = *(const f32x4*)(asrc + k0);
            va1 = *(const f32x4*)(asrc + k0 + 4);
            va2 = *(const f32x4*)(asrc + k0 + 8);
            va3 = *(const f32x4*)(asrc + k0 + 12);
        }
        // phase 2: compute on current buffer
        #pragma unroll
        for (int ks = 0; ks < 2; ++ks) {
            int cbase = ks * 4 + (lane >> 4);
            bf16x8 af[4], bfv[4];
            #pragma unroll
            for (int m = 0; m < 4; ++m) {
                int row = m * 16 + (lane & 15);
                af[m] = *(const bf16x8*)&As[cur][row * 64 + ((cbase ^ (row & 7)) * 8)];
            }
            #pragma unroll
            for (int n = 0; n < 4; ++n) {
                int hr = w * 64 + n * 16 + (lane & 15);
                bfv[n] = *(const bf16x8*)&Bs[cur][hr * 64 + ((cbase ^ (hr & 7)) * 8)];
            }
            #pragma unroll
            for (int m = 0; m < 4; ++m)
                #pragma unroll
                for (int n = 0; n < 4; ++n)
                    acc[m][n] = __builtin_amdgcn_mfma_f32_16x16x32_bf16(af[m], bfv[n], acc[m][n], 0, 0, 0);
        }
        // phase 3: A pack + LDS write for next round (vmcnt wait lands here, after compute)
        if (kr < 15) packA(nxt, va0, va1, va2, va3);
        __syncthreads();
    }

    // epilogue: tanh * g, reduce over this block's 256 cols
    float part[4][4];
    #pragma unroll
    for (int m = 0; m < 4; m++)
        #pragma unroll
        for (int j = 0; j < 4; j++) part[m][j] = 0.f;
    #pragma unroll
    for (int m = 0; m < 4; ++m)
        #pragma unroll
        for (int n = 0; n < 4; ++n) {
            float gv = gr[n];
            f32x4 v = acc[m][n];
            #pragma unroll
            for (int j = 0; j < 4; ++j) part[m][j] += fast_tanh(v[j]) * gv;
        }
    #pragma unroll
    for (int mask = 1; mask < 16; mask <<= 1)
        #pragma unroll
        for (int m = 0; m < 4; ++m)
            #pragma unroll
            for (int j = 0; j < 4; ++j)
                part[m][j] += __shfl_xor(part[m][j], mask, 64);

    float* red = (float*)As;  // alias: As no longer needed (post final barrier)
    if ((lane & 15) == 0) {
        int hi = lane >> 4;
        #pragma unroll
        for (int m = 0; m < 4; ++m)
            #pragma unroll
            for (int j = 0; j < 4; ++j)
                red[w * 64 + m * 16 + hi * 4 + j] = part[m][j];
    }
    __syncthreads();
    if (tid < 64) {
        float s = red[tid] + red[64 + tid] + red[128 + tid] + red[192 + tid];
        sp[(size_t)ch * (BB * PP) + b * PP + p0 + tid] = s;
    }
}

// ---- kernel 3: sum the 2 col-half partials + softmax over P per batch ----
__global__ __launch_bounds__(576) void k_softmax(const float* __restrict__ sp,
                                                 float* __restrict__ alpha) {
    int b = blockIdx.x;
    int t = threadIdx.x;  // 0..575
    __shared__ float red[9];
    float s = sp[b * PP + t] + sp[BB * PP + b * PP + t];
    float m = s;
    #pragma unroll
    for (int off = 32; off; off >>= 1) m = fmaxf(m, __shfl_xor(m, off, 64));
    int w = t >> 6;
    if ((t & 63) == 0) red[w] = m;
    __syncthreads();
    float gm = red[0];
    #pragma unroll
    for (int i = 1; i < 9; i++) gm = fmaxf(gm, red[i]);
    float e = __expf(s - gm);
    float sum = e;
    #pragma unroll
    for (int off = 32; off; off >>= 1) sum += __shfl_xor(sum, off, 64);
    __syncthreads();
    if ((t & 63) == 0) red[w] = sum;
    __syncthreads();
    float gsum = 0.f;
    #pragma unroll
    for (int i = 0; i < 9; i++) gsum += red[i];
    alpha[b * PP + t] = e / gsum;
}

// ---- kernel 4: partial weighted sums over 64-patch chunks ----
__global__ __launch_bounds__(256) void k_attend(const float* __restrict__ img,
                                                const float* __restrict__ alpha,
                                                float* __restrict__ part) {
    int b = blockIdx.y;
    int pc = blockIdx.x;  // 0..8
    int t = threadIdx.x;
    __shared__ float al[64];
    if (t < 64) al[t] = alpha[b * PP + pc * 64 + t];
    __syncthreads();
    int d = t * 4;
    f32x4 acc = (f32x4)0.f;
    const float* base = img + ((size_t)b * PP + (size_t)pc * 64) * DD + d;
    #pragma unroll 4
    for (int i = 0; i < 64; i++) {
        f32x4 v = *(const f32x4*)(base + (size_t)i * DD);
        acc += al[i] * v;
    }
    float* o = part + ((size_t)pc * BB + b) * DD + d;
    *(f32x4*)o = acc;
}

// ---- kernel 5: reduce the 9 partials ----
__global__ __launch_bounds__(256) void k_reduce(const float* __restrict__ part,
                                                float* __restrict__ out) {
    int i = blockIdx.x * 256 + threadIdx.x;  // 0..65535
    float s = 0.f;
    #pragma unroll
    for (int pc = 0; pc < 9; pc++) s += part[pc * (BB * DD) + i];
    out[i] = s;
}

extern "C" void kernel_launch(void* const* d_in, const int* in_sizes, int n_in,
                              void* d_out, int out_size, void* d_ws, size_t ws_size,
                              hipStream_t stream) {
    const float* seq   = (const float*)d_in[0];   // [64,1024]
    const float* img   = (const float*)d_in[1];   // [64,576,1024]
    const float* W_seq = (const float*)d_in[2];   // [512,1024]
    const float* W_img = (const float*)d_in[3];   // [512,1024]
    const float* W_w   = (const float*)d_in[4];   // [1,512]
    float* out = (float*)d_out;                   // [64,1024]

    char* ws = (char*)d_ws;
    unsigned short* Wb = (unsigned short*)ws;                        // 1 MB
    float* g      = (float*)(ws + 1048576);                          // 128 KB
    float* sp     = (float*)(ws + 1048576 + 131072);                 // 2*144 KB (partial scores)
    float* alpha  = (float*)(ws + 1048576 + 131072 + 294912);        // 144 KB
    float* part   = (float*)(ws + 1048576 + 131072 + 294912 + 147456); // 2.25 MB

    k_convert<<<512, 256, 0, stream>>>(W_img, Wb);
    k_seq<<<dim3(BB, 4), 128, 0, stream>>>(seq, W_seq, W_w, g);
    k_scores<<<dim3(18, BB), 256, 0, stream>>>(img, Wb, g, sp);
    k_softmax<<<BB, 576, 0, stream>>>(sp, alpha);
    k_attend<<<dim3(9, BB), 256, 0, stream>>>(img, alpha, part);
    k_reduce<<<256, 256, 0, stream>>>(part, out);
}

// Round 4
// 143.224 us; speedup vs baseline: 1.0635x; 1.0635x over previous
//
#include <hip/hip_runtime.h>
#include <hip/hip_bf16.h>

#define BB 64
#define PP 576
#define DD 1024
#define HH 512

typedef __attribute__((ext_vector_type(4))) float f32x4;
typedef __attribute__((ext_vector_type(8))) short bf16x8;

__device__ __forceinline__ unsigned short f2bf(float f) {
    union { float f; unsigned u; } v; v.f = f;
    unsigned r = v.u + 0x7FFF + ((v.u >> 16) & 1);
    return (unsigned short)(r >> 16);
}

__device__ __forceinline__ float fast_tanh(float x) {
    float e = __expf(2.f * x);
    return 1.f - 2.f / (e + 1.f);
}

__device__ __forceinline__ void gload16(const void* g, void* l) {
    __builtin_amdgcn_global_load_lds((const __attribute__((address_space(1))) unsigned int*)g,
                                     (__attribute__((address_space(3))) unsigned int*)l,
                                     16, 0, 0);
}

// ---- kernel 0: convert W_img fp32 -> bf16 in ws ----
__global__ __launch_bounds__(256) void k_convert(const float* __restrict__ w,
                                                 unsigned short* __restrict__ o) {
    int i = (blockIdx.x * 256 + threadIdx.x) * 4;
    f32x4 v = *(const f32x4*)(w + i);
    ushort4 r;
    r.x = f2bf(v.x); r.y = f2bf(v.y); r.z = f2bf(v.z); r.w = f2bf(v.w);
    *(ushort4*)(o + i) = r;
}

// ---- kernel 1: g[b][h] = tanh(seq[b]·W_seq[h]) * W_w[h]  (fp32 exact path) ----
__global__ __launch_bounds__(128) void k_seq(const float* __restrict__ seq,
                                             const float* __restrict__ W_seq,
                                             const float* __restrict__ W_w,
                                             float* __restrict__ g) {
    int b = blockIdx.x;
    int h = blockIdx.y * 128 + threadIdx.x;
    __shared__ float s_seq[DD];
    #pragma unroll
    for (int i = 0; i < 8; i++) s_seq[threadIdx.x + i * 128] = seq[b * DD + threadIdx.x + i * 128];
    __syncthreads();
    const float* wr = W_seq + (size_t)h * DD;
    float acc = 0.f;
    #pragma unroll 4
    for (int d = 0; d < DD; d += 4) {
        f32x4 w4 = *(const f32x4*)(wr + d);
        acc += w4.x * s_seq[d] + w4.y * s_seq[d + 1] + w4.z * s_seq[d + 2] + w4.w * s_seq[d + 3];
    }
    g[b * HH + h] = fast_tanh(acc) * W_w[h];
}

// ---- kernel 2: partial scores, counted-vmcnt software pipeline ----
// Block: 256 thr = 4 waves, 4 blocks/CU (40 KB LDS). Tile BM=64 x HC=256, BK=32, 32 rounds.
// Wave w owns B-cols [w*64,(w+1)*64) AND stages exactly those rows -> B sync is per-wave
// vmcnt only. Shared A-tile syncs via one raw s_barrier + lgkmcnt(0) per round (no vmcnt
// drain -> B prefetch stays in flight across the barrier).
// LDS rows = 32 bf16 (64B), 16B chunks XOR-swizzled: chunk_sw = chunk ^ ((row>>1)&3)
// (8 distinct bank slots x2 lanes = 2-way, free). A reg-staged (swizzled ds_write);
// B via global_load_lds with pre-swizzled global source (linear LDS dest).
__global__ __launch_bounds__(256, 4) void k_scores(const float* __restrict__ img,
                                                   const unsigned short* __restrict__ Wb,
                                                   const float* __restrict__ g,
                                                   float* __restrict__ sp) {
    int b = blockIdx.y;
    int rt = blockIdx.x % 9;
    int ch = blockIdx.x / 9;
    int p0 = rt * 64;
    int h0 = ch * 256;
    int tid = threadIdx.x;
    int w = tid >> 6, lane = tid & 63;

    __shared__ unsigned short As[2][64 * 32];    // 2 x 4 KB
    __shared__ unsigned short Bs[2][256 * 32];   // 2 x 16 KB -> 40 KB total

    float gr[4];
    #pragma unroll
    for (int n = 0; n < 4; ++n) gr[n] = g[b * HH + h0 + w * 64 + n * 16 + (lane & 15)];

    f32x4 acc[4][4];
    #pragma unroll
    for (int m = 0; m < 4; m++)
        #pragma unroll
        for (int n = 0; n < 4; n++) acc[m][n] = (f32x4)0.f;

    // A: thread t -> row t>>2 (0..63), 8 f32 at col (t&3)*8
    int arow = tid >> 2;
    int acnk = tid & 3;
    const float* asrc = img + ((size_t)(b * PP + p0 + arow)) * DD + acnk * 8;
    int aw = arow * 32 + ((acnk ^ ((arow >> 1) & 3)) * 8);

    // B: issue i covers rows w*64+i*16 + (lane>>2), chunk lane&3, source pre-swizzled
    int rl = lane >> 2;
    int bswz = (lane & 3) ^ ((rl >> 1) & 3);
    const unsigned short* bbase = Wb + (size_t)h0 * DD;

    f32x4 u0, u1;

    // ---- prologue: round 0 ----
    u0 = *(const f32x4*)(asrc);
    u1 = *(const f32x4*)(asrc + 4);
    __builtin_amdgcn_sched_barrier(0);
    #pragma unroll
    for (int i = 0; i < 4; ++i) {
        int hr = w * 64 + i * 16 + rl;
        gload16(bbase + (size_t)hr * DD + bswz * 8, &Bs[0][(w * 4 + i) * 512]);
    }
    asm volatile("s_waitcnt vmcnt(4)" ::: "memory");   // A(0) ready; B(0) in flight
    {
        bf16x8 p;
        p[0] = (short)f2bf(u0.x); p[1] = (short)f2bf(u0.y);
        p[2] = (short)f2bf(u0.z); p[3] = (short)f2bf(u0.w);
        p[4] = (short)f2bf(u1.x); p[5] = (short)f2bf(u1.y);
        p[6] = (short)f2bf(u1.z); p[7] = (short)f2bf(u1.w);
        *(bf16x8*)&As[0][aw] = p;
    }
    asm volatile("s_waitcnt lgkmcnt(0)" ::: "memory");
    __builtin_amdgcn_s_barrier();

    int r15 = lane & 15;
    int csw = (lane >> 4) ^ ((r15 >> 1) & 3);

    for (int kr = 0; kr < 32; ++kr) {
        int cur = kr & 1, nxt = cur ^ 1;
        if (kr < 31) {
            int k0 = (kr + 1) * 32;
            u0 = *(const f32x4*)(asrc + k0);       // 2 vmem (A next)
            u1 = *(const f32x4*)(asrc + k0 + 4);
            __builtin_amdgcn_sched_barrier(0);      // pin: A issued before B
            #pragma unroll
            for (int i = 0; i < 4; ++i) {          // 4 vmem (B next)
                int hr = w * 64 + i * 16 + rl;
                gload16(bbase + (size_t)hr * DD + k0 + bswz * 8, &Bs[nxt][(w * 4 + i) * 512]);
            }
            // retire the 4 B(cur) loads; 2 A + 4 B stay in flight
            asm volatile("s_waitcnt vmcnt(6)" ::: "memory");
        } else {
            asm volatile("s_waitcnt vmcnt(0)" ::: "memory");
        }
        // compute on cur
        {
            bf16x8 af[4], bfv[4];
            #pragma unroll
            for (int m = 0; m < 4; ++m)
                af[m] = *(const bf16x8*)&As[cur][(m * 16 + r15) * 32 + csw * 8];
            #pragma unroll
            for (int n = 0; n < 4; ++n)
                bfv[n] = *(const bf16x8*)&Bs[cur][(w * 64 + n * 16 + r15) * 32 + csw * 8];
            #pragma unroll
            for (int m = 0; m < 4; ++m)
                #pragma unroll
                for (int n = 0; n < 4; ++n)
                    acc[m][n] = __builtin_amdgcn_mfma_f32_16x16x32_bf16(af[m], bfv[n], acc[m][n], 0, 0, 0);
        }
        if (kr < 31) {
            // retire A(next) only; B(next) still in flight across the barrier
            asm volatile("s_waitcnt vmcnt(4)" ::: "memory");
            bf16x8 p;
            p[0] = (short)f2bf(u0.x); p[1] = (short)f2bf(u0.y);
            p[2] = (short)f2bf(u0.z); p[3] = (short)f2bf(u0.w);
            p[4] = (short)f2bf(u1.x); p[5] = (short)f2bf(u1.y);
            p[6] = (short)f2bf(u1.z); p[7] = (short)f2bf(u1.w);
            *(bf16x8*)&As[nxt][aw] = p;
            asm volatile("s_waitcnt lgkmcnt(0)" ::: "memory");
            __builtin_amdgcn_s_barrier();
        }
    }

    // epilogue: tanh * g, reduce over this block's 256 cols
    float part[4][4];
    #pragma unroll
    for (int m = 0; m < 4; m++)
        #pragma unroll
        for (int j = 0; j < 4; j++) part[m][j] = 0.f;
    #pragma unroll
    for (int m = 0; m < 4; ++m)
        #pragma unroll
        for (int n = 0; n < 4; ++n) {
            float gv = gr[n];
            f32x4 v = acc[m][n];
            #pragma unroll
            for (int j = 0; j < 4; ++j) part[m][j] += fast_tanh(v[j]) * gv;
        }
    #pragma unroll
    for (int mask = 1; mask < 16; mask <<= 1)
        #pragma unroll
        for (int m = 0; m < 4; ++m)
            #pragma unroll
            for (int j = 0; j < 4; ++j)
                part[m][j] += __shfl_xor(part[m][j], mask, 64);

    float* red = (float*)&As[0][0];  // alias buffer 0 (round 31 used buffer 1)
    if ((lane & 15) == 0) {
        int hi = lane >> 4;
        #pragma unroll
        for (int m = 0; m < 4; ++m)
            #pragma unroll
            for (int j = 0; j < 4; ++j)
                red[w * 64 + m * 16 + hi * 4 + j] = part[m][j];
    }
    __syncthreads();
    if (tid < 64) {
        float s = red[tid] + red[64 + tid] + red[128 + tid] + red[192 + tid];
        sp[(size_t)ch * (BB * PP) + b * PP + p0 + tid] = s;
    }
}

// ---- kernel 3: sum the 2 col-half partials + softmax over P per batch ----
__global__ __launch_bounds__(576) void k_softmax(const float* __restrict__ sp,
                                                 float* __restrict__ alpha) {
    int b = blockIdx.x;
    int t = threadIdx.x;  // 0..575
    __shared__ float red[9];
    float s = sp[b * PP + t] + sp[BB * PP + b * PP + t];
    float m = s;
    #pragma unroll
    for (int off = 32; off; off >>= 1) m = fmaxf(m, __shfl_xor(m, off, 64));
    int w = t >> 6;
    if ((t & 63) == 0) red[w] = m;
    __syncthreads();
    float gm = red[0];
    #pragma unroll
    for (int i = 1; i < 9; i++) gm = fmaxf(gm, red[i]);
    float e = __expf(s - gm);
    float sum = e;
    #pragma unroll
    for (int off = 32; off; off >>= 1) sum += __shfl_xor(sum, off, 64);
    __syncthreads();
    if ((t & 63) == 0) red[w] = sum;
    __syncthreads();
    float gsum = 0.f;
    #pragma unroll
    for (int i = 0; i < 9; i++) gsum += red[i];
    alpha[b * PP + t] = e / gsum;
}

// ---- kernel 4: partial weighted sums over 64-patch chunks ----
__global__ __launch_bounds__(256) void k_attend(const float* __restrict__ img,
                                                const float* __restrict__ alpha,
                                                float* __restrict__ part) {
    int b = blockIdx.y;
    int pc = blockIdx.x;  // 0..8
    int t = threadIdx.x;
    __shared__ float al[64];
    if (t < 64) al[t] = alpha[b * PP + pc * 64 + t];
    __syncthreads();
    int d = t * 4;
    f32x4 acc = (f32x4)0.f;
    const float* base = img + ((size_t)b * PP + (size_t)pc * 64) * DD + d;
    #pragma unroll 4
    for (int i = 0; i < 64; i++) {
        f32x4 v = *(const f32x4*)(base + (size_t)i * DD);
        acc += al[i] * v;
    }
    float* o = part + ((size_t)pc * BB + b) * DD + d;
    *(f32x4*)o = acc;
}

// ---- kernel 5: reduce the 9 partials ----
__global__ __launch_bounds__(256) void k_reduce(const float* __restrict__ part,
                                                float* __restrict__ out) {
    int i = blockIdx.x * 256 + threadIdx.x;  // 0..65535
    float s = 0.f;
    #pragma unroll
    for (int pc = 0; pc < 9; pc++) s += part[pc * (BB * DD) + i];
    out[i] = s;
}

extern "C" void kernel_launch(void* const* d_in, const int* in_sizes, int n_in,
                              void* d_out, int out_size, void* d_ws, size_t ws_size,
                              hipStream_t stream) {
    const float* seq   = (const float*)d_in[0];   // [64,1024]
    const float* img   = (const float*)d_in[1];   // [64,576,1024]
    const float* W_seq = (const float*)d_in[2];   // [512,1024]
    const float* W_img = (const float*)d_in[3];   // [512,1024]
    const float* W_w   = (const float*)d_in[4];   // [1,512]
    float* out = (float*)d_out;                   // [64,1024]

    char* ws = (char*)d_ws;
    unsigned short* Wb = (unsigned short*)ws;                        // 1 MB
    float* g      = (float*)(ws + 1048576);                          // 128 KB
    float* sp     = (float*)(ws + 1048576 + 131072);                 // 2*144 KB (partial scores)
    float* alpha  = (float*)(ws + 1048576 + 131072 + 294912);        // 144 KB
    float* part   = (float*)(ws + 1048576 + 131072 + 294912 + 147456); // 2.25 MB

    k_convert<<<512, 256, 0, stream>>>(W_img, Wb);
    k_seq<<<dim3(BB, 4), 128, 0, stream>>>(seq, W_seq, W_w, g);
    k_scores<<<dim3(18, BB), 256, 0, stream>>>(img, Wb, g, sp);
    k_softmax<<<BB, 576, 0, stream>>>(sp, alpha);
    k_attend<<<dim3(9, BB), 256, 0, stream>>>(img, alpha, part);
    k_reduce<<<256, 256, 0, stream>>>(part, out);
}